// Round 1
// baseline (2951.948 us; speedup 1.0000x reference)
//
#include <hip/hip_runtime.h>

#define NUM_USERS 200000
#define NUM_ITEMS 100000
#define N_NODES   300000
#define NNZ       4000000
#define DIM       64

// Total embedding elements
#define N_ELEM   ((size_t)N_NODES * DIM)       // 19,200,000
#define N_USER_E ((size_t)NUM_USERS * DIM)     // 12,800,000

// ---------------------------------------------------------------------------
// init: cur = concat(user_emb, item_emb); out = 0.25f * cur   (float4)
// N_USER_E = 12.8M is divisible by 4, so the concat boundary is float4-safe.
// ---------------------------------------------------------------------------
__global__ void lgcn_init(const float4* __restrict__ user_emb,
                          const float4* __restrict__ item_emb,
                          float4* __restrict__ cur,
                          float4* __restrict__ out) {
    size_t i = (size_t)blockIdx.x * blockDim.x + threadIdx.x;
    const size_t n4 = N_ELEM / 4;        // 4.8M
    const size_t nu4 = N_USER_E / 4;     // 3.2M
    if (i >= n4) return;
    float4 v = (i < nu4) ? user_emb[i] : item_emb[i - nu4];
    cur[i] = v;
    float4 o;
    o.x = 0.25f * v.x; o.y = 0.25f * v.y; o.z = 0.25f * v.z; o.w = 0.25f * v.w;
    out[i] = o;
}

// ---------------------------------------------------------------------------
// SpMM: one wave (64 lanes) per edge; lane = latent dim.
// Gather cur[col*64+lane] (coalesced 256B) and atomicAdd into next[row*64+lane]
// (64 consecutive fp32 -> packed same-cacheline atomics at L2).
// ---------------------------------------------------------------------------
__global__ void lgcn_spmm(const float* __restrict__ vals,
                          const int*   __restrict__ rows,
                          const int*   __restrict__ cols,
                          const float* __restrict__ cur,
                          float*       __restrict__ next) {
    size_t tid  = (size_t)blockIdx.x * blockDim.x + threadIdx.x;
    size_t edge = tid >> 6;
    int    lane = (int)(tid & 63);
    if (edge >= NNZ) return;
    int   r = rows[edge];
    int   c = cols[edge];
    float v = vals[edge];
    float x = cur[(size_t)c * DIM + lane];
    atomicAdd(&next[(size_t)r * DIM + lane], v * x);
}

// ---------------------------------------------------------------------------
// acc: out += 0.25 * next   (float4)
// ---------------------------------------------------------------------------
__global__ void lgcn_acc(float4* __restrict__ out,
                         const float4* __restrict__ next) {
    size_t i = (size_t)blockIdx.x * blockDim.x + threadIdx.x;
    const size_t n4 = N_ELEM / 4;
    if (i >= n4) return;
    float4 o = out[i];
    float4 v = next[i];
    o.x += 0.25f * v.x; o.y += 0.25f * v.y; o.z += 0.25f * v.z; o.w += 0.25f * v.w;
    out[i] = o;
}

extern "C" void kernel_launch(void* const* d_in, const int* in_sizes, int n_in,
                              void* d_out, int out_size, void* d_ws, size_t ws_size,
                              hipStream_t stream) {
    const float* user_emb = (const float*)d_in[0];
    const float* item_emb = (const float*)d_in[1];
    const float* vals     = (const float*)d_in[2];
    const int*   rows     = (const int*)d_in[3];
    const int*   cols     = (const int*)d_in[4];
    float* out = (float*)d_out;

    // workspace: two ping-pong embedding buffers (76.8 MB each)
    float* cur = (float*)d_ws;
    float* nxt = cur + N_ELEM;

    const int BLK = 256;
    const size_t n4 = N_ELEM / 4;
    dim3 grid_elem((unsigned)((n4 + BLK - 1) / BLK));
    // one wave per edge -> NNZ*64 threads
    dim3 grid_spmm((unsigned)(((size_t)NNZ * 64 + BLK - 1) / BLK));

    lgcn_init<<<grid_elem, BLK, 0, stream>>>(
        (const float4*)user_emb, (const float4*)item_emb,
        (float4*)cur, (float4*)out);

    for (int layer = 0; layer < 3; ++layer) {
        hipMemsetAsync(nxt, 0, N_ELEM * sizeof(float), stream);
        lgcn_spmm<<<grid_spmm, BLK, 0, stream>>>(vals, rows, cols, cur, nxt);
        lgcn_acc<<<grid_elem, BLK, 0, stream>>>((float4*)out, (const float4*)nxt);
        float* t = cur; cur = nxt; nxt = t;   // host-side swap, identical every call
    }
}

// Round 2
// 1177.967 us; speedup vs baseline: 2.5060x; 2.5060x over previous
//
#include <hip/hip_runtime.h>

#define NUM_USERS 200000
#define NUM_ITEMS 100000
#define N_NODES   300000
#define NNZ       4000000
#define DIM       64
#define N_ELEM   ((size_t)N_NODES * DIM)   // 19,200,000 floats

// ---------------------------------------------------------------------------
// Build step 1: row histogram. 4M int atomics over 300k bins (L2-resident).
// ---------------------------------------------------------------------------
__global__ void lgcn_hist(const int* __restrict__ rows, int* __restrict__ cnt) {
    int e = blockIdx.x * blockDim.x + threadIdx.x;
    if (e < NNZ) atomicAdd(&cnt[rows[e]], 1);
}

// ---------------------------------------------------------------------------
// Build step 2: segment allocation WITHOUT a scan. Wave-level inclusive scan
// of counts (shfl), one atomicAdd on a global cursor per wave. Segments are
// contiguous & disjoint; absolute order is irrelevant.
// ---------------------------------------------------------------------------
__global__ void lgcn_alloc(const int* __restrict__ cnt, int* __restrict__ base,
                           int* __restrict__ fill, int* __restrict__ cursor) {
    int r = blockIdx.x * blockDim.x + threadIdx.x;
    int lane = threadIdx.x & 63;
    int c = (r < N_NODES) ? cnt[r] : 0;
    int s = c;
    #pragma unroll
    for (int o = 1; o < 64; o <<= 1) {
        int t = __shfl_up(s, o);
        if (lane >= o) s += t;
    }
    int total = __shfl(s, 63);
    int wbase = 0;
    if (lane == 63) wbase = atomicAdd(cursor, total);
    wbase = __shfl(wbase, 63);
    if (r < N_NODES) {
        int b = wbase + (s - c);   // exclusive prefix within wave
        base[r] = b;
        fill[r] = b;
    }
}

// ---------------------------------------------------------------------------
// Build step 3: scatter (col,val) into row segments.
// ---------------------------------------------------------------------------
__global__ void lgcn_scatter(const int* __restrict__ rows, const int* __restrict__ cols,
                             const float* __restrict__ vals, int* __restrict__ fill,
                             int* __restrict__ sc_col, float* __restrict__ sc_val) {
    int e = blockIdx.x * blockDim.x + threadIdx.x;
    if (e >= NNZ) return;
    int r = rows[e];
    int p = atomicAdd(&fill[r], 1);
    sc_col[p] = cols[e];
    sc_val[p] = vals[e];
}

// ---------------------------------------------------------------------------
// CSR SpMM, one wave per row, lane = latent dim (64 lanes == 64 dims).
// MODE 0 (layer 1): gather from concat(user,item); out = 0.25*(own + acc); nxt = acc
// MODE 1 (layer 2): gather cur; out += 0.25*acc; nxt = acc
// MODE 2 (layer 3): gather cur; out += 0.25*acc; no nxt write
// ---------------------------------------------------------------------------
template<int MODE>
__global__ __launch_bounds__(256) void lgcn_spmm_csr(
    const int* __restrict__ base, const int* __restrict__ cnt,
    const int* __restrict__ sc_col, const float* __restrict__ sc_val,
    const float* __restrict__ user_emb, const float* __restrict__ item_emb,
    const float* __restrict__ cur, float* __restrict__ nxt, float* __restrict__ out)
{
    int row  = blockIdx.x * 4 + (threadIdx.x >> 6);
    int lane = threadIdx.x & 63;
    if (row >= N_NODES) return;
    int b = base[row];
    int n = cnt[row];
    float acc = 0.f;

    for (int k0 = 0; k0 < n; k0 += 64) {
        int m = min(64, n - k0);
        int c = 0; float v = 0.f;
        if (lane < m) {
            int idx = b + k0 + lane;
            c = sc_col[idx];
            v = sc_val[idx];
        }
        int j = 0;
        for (; j + 4 <= m; j += 4) {
            int c0 = __shfl(c, j+0), c1 = __shfl(c, j+1),
                c2 = __shfl(c, j+2), c3 = __shfl(c, j+3);
            float v0 = __shfl(v, j+0), v1 = __shfl(v, j+1),
                  v2 = __shfl(v, j+2), v3 = __shfl(v, j+3);
            float x0, x1, x2, x3;
            if constexpr (MODE == 0) {
                x0 = (c0 < NUM_USERS) ? user_emb[(size_t)c0*DIM + lane]
                                      : item_emb[(size_t)(c0-NUM_USERS)*DIM + lane];
                x1 = (c1 < NUM_USERS) ? user_emb[(size_t)c1*DIM + lane]
                                      : item_emb[(size_t)(c1-NUM_USERS)*DIM + lane];
                x2 = (c2 < NUM_USERS) ? user_emb[(size_t)c2*DIM + lane]
                                      : item_emb[(size_t)(c2-NUM_USERS)*DIM + lane];
                x3 = (c3 < NUM_USERS) ? user_emb[(size_t)c3*DIM + lane]
                                      : item_emb[(size_t)(c3-NUM_USERS)*DIM + lane];
            } else {
                x0 = cur[(size_t)c0*DIM + lane];
                x1 = cur[(size_t)c1*DIM + lane];
                x2 = cur[(size_t)c2*DIM + lane];
                x3 = cur[(size_t)c3*DIM + lane];
            }
            acc += v0*x0;
            acc += v1*x1;
            acc += v2*x2;
            acc += v3*x3;
        }
        for (; j < m; ++j) {
            int cj = __shfl(c, j);
            float vj = __shfl(v, j);
            float xj;
            if constexpr (MODE == 0) {
                xj = (cj < NUM_USERS) ? user_emb[(size_t)cj*DIM + lane]
                                      : item_emb[(size_t)(cj-NUM_USERS)*DIM + lane];
            } else {
                xj = cur[(size_t)cj*DIM + lane];
            }
            acc += vj*xj;
        }
    }

    size_t o = (size_t)row * DIM + lane;
    if constexpr (MODE == 0) {
        float own = (row < NUM_USERS) ? user_emb[o]
                                      : item_emb[(size_t)(row - NUM_USERS)*DIM + lane];
        nxt[o] = acc;
        out[o] = 0.25f * (own + acc);
    } else if constexpr (MODE == 1) {
        nxt[o] = acc;
        out[o] += 0.25f * acc;
    } else {
        out[o] += 0.25f * acc;
    }
}

extern "C" void kernel_launch(void* const* d_in, const int* in_sizes, int n_in,
                              void* d_out, int out_size, void* d_ws, size_t ws_size,
                              hipStream_t stream) {
    const float* user_emb = (const float*)d_in[0];
    const float* item_emb = (const float*)d_in[1];
    const float* vals     = (const float*)d_in[2];
    const int*   rows     = (const int*)d_in[3];
    const int*   cols     = (const int*)d_in[4];
    float* out = (float*)d_out;

    // ---- workspace carve-up (~189.2 MB) ----
    char* ws = (char*)d_ws;
    size_t off = 0;
    float* buf0   = (float*)(ws + off); off += N_ELEM * 4;          // 76.8 MB
    float* buf1   = (float*)(ws + off); off += N_ELEM * 4;          // 76.8 MB
    int*   sc_col = (int*)  (ws + off); off += (size_t)NNZ * 4;     // 16 MB
    float* sc_val = (float*)(ws + off); off += (size_t)NNZ * 4;     // 16 MB
    int*   row_cnt  = (int*)(ws + off); off += (size_t)N_NODES * 4; // 1.2 MB
    int*   cursor   = (int*)(ws + off); off += 256;                 // zeroed with row_cnt
    int*   row_base = (int*)(ws + off); off += (size_t)N_NODES * 4;
    int*   row_fill = (int*)(ws + off); off += (size_t)N_NODES * 4;

    const int BLK = 256;
    dim3 grid_edge((NNZ + BLK - 1) / BLK);                // 15625
    dim3 grid_node((N_NODES + BLK - 1) / BLK);            // 1172
    dim3 grid_spmm((N_NODES + 3) / 4);                    // 75000 (4 rows/block)

    // ---- build CSR (once per call; ws is re-poisoned each launch) ----
    hipMemsetAsync(row_cnt, 0, (size_t)N_NODES * 4 + 256, stream);  // cnt + cursor
    lgcn_hist<<<grid_edge, BLK, 0, stream>>>(rows, row_cnt);
    lgcn_alloc<<<grid_node, BLK, 0, stream>>>(row_cnt, row_base, row_fill, cursor);
    lgcn_scatter<<<grid_edge, BLK, 0, stream>>>(rows, cols, vals, row_fill,
                                                sc_col, sc_val);

    // ---- 3 fused propagation layers ----
    lgcn_spmm_csr<0><<<grid_spmm, BLK, 0, stream>>>(
        row_base, row_cnt, sc_col, sc_val, user_emb, item_emb,
        nullptr, buf0, out);
    lgcn_spmm_csr<1><<<grid_spmm, BLK, 0, stream>>>(
        row_base, row_cnt, sc_col, sc_val, nullptr, nullptr,
        buf0, buf1, out);
    lgcn_spmm_csr<2><<<grid_spmm, BLK, 0, stream>>>(
        row_base, row_cnt, sc_col, sc_val, nullptr, nullptr,
        buf1, nullptr, out);
}

// Round 3
// 1129.797 us; speedup vs baseline: 2.6128x; 1.0426x over previous
//
#include <hip/hip_runtime.h>

#define NUM_USERS 200000
#define NUM_ITEMS 100000
#define N_NODES   300000
#define NNZ       4000000
#define DIM       64
#define N_ELEM   ((size_t)N_NODES * DIM)   // 19,200,000 floats

// ---------------------------------------------------------------------------
// Build step 1: row histogram. int4-vectorized reads; 4M atomics over 300k
// L2-resident bins. NNZ % 4 == 0.
// ---------------------------------------------------------------------------
__global__ void lgcn_hist(const int4* __restrict__ rows4, int* __restrict__ cnt) {
    int i = blockIdx.x * blockDim.x + threadIdx.x;
    if (i >= NNZ / 4) return;
    int4 r = rows4[i];
    atomicAdd(&cnt[r.x], 1);
    atomicAdd(&cnt[r.y], 1);
    atomicAdd(&cnt[r.z], 1);
    atomicAdd(&cnt[r.w], 1);
}

// ---------------------------------------------------------------------------
// Build step 2: segment allocation without a scan. Wave-level inclusive scan
// (shfl) + one atomicAdd on a global cursor per wave. Writes packed {base,cnt}
// row descriptor, plus fill cursor per row.
// ---------------------------------------------------------------------------
__global__ void lgcn_alloc(const int* __restrict__ cnt, int2* __restrict__ desc,
                           int* __restrict__ fill, int* __restrict__ cursor) {
    int r = blockIdx.x * blockDim.x + threadIdx.x;
    int lane = threadIdx.x & 63;
    int c = (r < N_NODES) ? cnt[r] : 0;
    int s = c;
    #pragma unroll
    for (int o = 1; o < 64; o <<= 1) {
        int t = __shfl_up(s, o);
        if (lane >= o) s += t;
    }
    int total = __shfl(s, 63);
    int wbase = 0;
    if (lane == 63) wbase = atomicAdd(cursor, total);
    wbase = __shfl(wbase, 63);
    if (r < N_NODES) {
        int b = wbase + (s - c);   // exclusive prefix within wave
        desc[r] = make_int2(b, c);
        fill[r] = b;
    }
}

// ---------------------------------------------------------------------------
// Build step 3: scatter packed (col,val) as ONE 8B write per edge.
// ---------------------------------------------------------------------------
__global__ void lgcn_scatter(const int* __restrict__ rows, const int* __restrict__ cols,
                             const float* __restrict__ vals, int* __restrict__ fill,
                             int2* __restrict__ sc) {
    int e = blockIdx.x * blockDim.x + threadIdx.x;
    if (e >= NNZ) return;
    int r = rows[e];
    int p = atomicAdd(&fill[r], 1);
    sc[p] = make_int2(cols[e], __float_as_int(vals[e]));
}

// ---------------------------------------------------------------------------
// CSR SpMM, one wave per row, lane = latent dim (64 lanes == 64 dims).
// MODE 0 (layer 1): gather concat(user,item); out = 0.25*(own + acc); nxt = acc
// MODE 1 (layer 2): gather cur; out += 0.25*acc; nxt = acc
// MODE 2 (layer 3): gather cur; out += 0.25*acc
// ---------------------------------------------------------------------------
template<int MODE>
__global__ __launch_bounds__(256) void lgcn_spmm_csr(
    const int2* __restrict__ desc, const int2* __restrict__ sc,
    const float* __restrict__ user_emb, const float* __restrict__ item_emb,
    const float* __restrict__ cur, float* __restrict__ nxt, float* __restrict__ out)
{
    int row  = blockIdx.x * 4 + (threadIdx.x >> 6);
    int lane = threadIdx.x & 63;
    if (row >= N_NODES) return;
    int2 d = desc[row];
    int b = d.x, n = d.y;
    float acc0 = 0.f, acc1 = 0.f, acc2 = 0.f, acc3 = 0.f;

    for (int k0 = 0; k0 < n; k0 += 64) {
        int m = min(64, n - k0);
        int c = 0, vbits = 0;
        if (lane < m) {
            int2 cv = sc[b + k0 + lane];
            c = cv.x; vbits = cv.y;
        }
        int j = 0;
        for (; j + 4 <= m; j += 4) {
            int c0 = __shfl(c, j+0), c1 = __shfl(c, j+1),
                c2 = __shfl(c, j+2), c3 = __shfl(c, j+3);
            float v0 = __int_as_float(__shfl(vbits, j+0));
            float v1 = __int_as_float(__shfl(vbits, j+1));
            float v2 = __int_as_float(__shfl(vbits, j+2));
            float v3 = __int_as_float(__shfl(vbits, j+3));
            float x0, x1, x2, x3;
            if constexpr (MODE == 0) {
                x0 = (c0 < NUM_USERS) ? user_emb[(size_t)c0*DIM + lane]
                                      : item_emb[(size_t)(c0-NUM_USERS)*DIM + lane];
                x1 = (c1 < NUM_USERS) ? user_emb[(size_t)c1*DIM + lane]
                                      : item_emb[(size_t)(c1-NUM_USERS)*DIM + lane];
                x2 = (c2 < NUM_USERS) ? user_emb[(size_t)c2*DIM + lane]
                                      : item_emb[(size_t)(c2-NUM_USERS)*DIM + lane];
                x3 = (c3 < NUM_USERS) ? user_emb[(size_t)c3*DIM + lane]
                                      : item_emb[(size_t)(c3-NUM_USERS)*DIM + lane];
            } else {
                x0 = cur[(size_t)c0*DIM + lane];
                x1 = cur[(size_t)c1*DIM + lane];
                x2 = cur[(size_t)c2*DIM + lane];
                x3 = cur[(size_t)c3*DIM + lane];
            }
            acc0 += v0*x0;
            acc1 += v1*x1;
            acc2 += v2*x2;
            acc3 += v3*x3;
        }
        for (; j < m; ++j) {
            int cj = __shfl(c, j);
            float vj = __int_as_float(__shfl(vbits, j));
            float xj;
            if constexpr (MODE == 0) {
                xj = (cj < NUM_USERS) ? user_emb[(size_t)cj*DIM + lane]
                                      : item_emb[(size_t)(cj-NUM_USERS)*DIM + lane];
            } else {
                xj = cur[(size_t)cj*DIM + lane];
            }
            acc0 += vj*xj;
        }
    }

    float acc = (acc0 + acc1) + (acc2 + acc3);
    size_t o = (size_t)row * DIM + lane;
    if constexpr (MODE == 0) {
        float own = (row < NUM_USERS) ? user_emb[o]
                                      : item_emb[(size_t)(row - NUM_USERS)*DIM + lane];
        nxt[o] = acc;
        out[o] = 0.25f * (own + acc);
    } else if constexpr (MODE == 1) {
        nxt[o] = acc;
        out[o] += 0.25f * acc;
    } else {
        out[o] += 0.25f * acc;
    }
}

extern "C" void kernel_launch(void* const* d_in, const int* in_sizes, int n_in,
                              void* d_out, int out_size, void* d_ws, size_t ws_size,
                              hipStream_t stream) {
    const float* user_emb = (const float*)d_in[0];
    const float* item_emb = (const float*)d_in[1];
    const float* vals     = (const float*)d_in[2];
    const int*   rows     = (const int*)d_in[3];
    const int*   cols     = (const int*)d_in[4];
    float* out = (float*)d_out;

    // ---- workspace carve-up (~190 MB) ----
    char* ws = (char*)d_ws;
    size_t off = 0;
    float* buf0   = (float*)(ws + off); off += N_ELEM * 4;            // 76.8 MB
    float* buf1   = (float*)(ws + off); off += N_ELEM * 4;            // 76.8 MB
    int2*  sc     = (int2*) (ws + off); off += (size_t)NNZ * 8;       // 32 MB
    int*   row_cnt  = (int*)(ws + off); off += (size_t)N_NODES * 4;   // 1.2 MB
    int*   cursor   = (int*)(ws + off); off += 256;                   // zeroed with cnt
    int2*  row_desc = (int2*)(ws + off); off += (size_t)N_NODES * 8;
    int*   row_fill = (int*)(ws + off); off += (size_t)N_NODES * 4;

    const int BLK = 256;
    dim3 grid_edge((NNZ + BLK - 1) / BLK);                 // 15625
    dim3 grid_edge4((NNZ / 4 + BLK - 1) / BLK);            // 3907
    dim3 grid_node((N_NODES + BLK - 1) / BLK);             // 1172
    dim3 grid_spmm((N_NODES + 3) / 4);                     // 75000 (4 rows/block)

    // ---- build CSR (once per call; ws re-poisoned before every launch) ----
    hipMemsetAsync(row_cnt, 0, (size_t)N_NODES * 4 + 256, stream);   // cnt + cursor
    lgcn_hist<<<grid_edge4, BLK, 0, stream>>>((const int4*)rows, row_cnt);
    lgcn_alloc<<<grid_node, BLK, 0, stream>>>(row_cnt, row_desc, row_fill, cursor);
    lgcn_scatter<<<grid_edge, BLK, 0, stream>>>(rows, cols, vals, row_fill, sc);

    // ---- 3 fused propagation layers ----
    lgcn_spmm_csr<0><<<grid_spmm, BLK, 0, stream>>>(
        row_desc, sc, user_emb, item_emb, nullptr, buf0, out);
    lgcn_spmm_csr<1><<<grid_spmm, BLK, 0, stream>>>(
        row_desc, sc, nullptr, nullptr, buf0, buf1, out);
    lgcn_spmm_csr<2><<<grid_spmm, BLK, 0, stream>>>(
        row_desc, sc, nullptr, nullptr, buf1, nullptr, out);
}

// Round 4
// 952.483 us; speedup vs baseline: 3.0992x; 1.1862x over previous
//
#include <hip/hip_runtime.h>

#define NUM_USERS 200000
#define NUM_ITEMS 100000
#define N_NODES   300000
#define NNZ       4000000
#define DIM       64
#define N_ELEM   ((size_t)N_NODES * DIM)   // 19,200,000 elements

// bf16 <-> fp32 helpers (finite values only; RNE rounding)
static __device__ __forceinline__ float bf2f(unsigned short v) {
    return __uint_as_float(((unsigned int)v) << 16);
}
static __device__ __forceinline__ unsigned short f2bf(float f) {
    unsigned int u = __float_as_uint(f);
    u = (u + 0x7FFF + ((u >> 16) & 1)) >> 16;   // round-to-nearest-even
    return (unsigned short)u;
}

// ---------------------------------------------------------------------------
// Build step 1: row histogram. int4-vectorized reads; 4M atomics over 300k
// L2-resident bins. NNZ % 4 == 0.
// ---------------------------------------------------------------------------
__global__ void lgcn_hist(const int4* __restrict__ rows4, int* __restrict__ cnt) {
    int i = blockIdx.x * blockDim.x + threadIdx.x;
    if (i >= NNZ / 4) return;
    int4 r = rows4[i];
    atomicAdd(&cnt[r.x], 1);
    atomicAdd(&cnt[r.y], 1);
    atomicAdd(&cnt[r.z], 1);
    atomicAdd(&cnt[r.w], 1);
}

// ---------------------------------------------------------------------------
// Build step 2: segment allocation without a scan. Wave-level inclusive scan
// (shfl) + one atomicAdd on a global cursor per wave. Writes packed {base,cnt}
// row descriptor, plus fill cursor per row.
// ---------------------------------------------------------------------------
__global__ void lgcn_alloc(const int* __restrict__ cnt, int2* __restrict__ desc,
                           int* __restrict__ fill, int* __restrict__ cursor) {
    int r = blockIdx.x * blockDim.x + threadIdx.x;
    int lane = threadIdx.x & 63;
    int c = (r < N_NODES) ? cnt[r] : 0;
    int s = c;
    #pragma unroll
    for (int o = 1; o < 64; o <<= 1) {
        int t = __shfl_up(s, o);
        if (lane >= o) s += t;
    }
    int total = __shfl(s, 63);
    int wbase = 0;
    if (lane == 63) wbase = atomicAdd(cursor, total);
    wbase = __shfl(wbase, 63);
    if (r < N_NODES) {
        int b = wbase + (s - c);   // exclusive prefix within wave
        desc[r] = make_int2(b, c);
        fill[r] = b;
    }
}

// ---------------------------------------------------------------------------
// Build step 3: scatter packed (col,val) as ONE 8B write per edge.
// ---------------------------------------------------------------------------
__global__ void lgcn_scatter(const int* __restrict__ rows, const int* __restrict__ cols,
                             const float* __restrict__ vals, int* __restrict__ fill,
                             int2* __restrict__ sc) {
    int e = blockIdx.x * blockDim.x + threadIdx.x;
    if (e >= NNZ) return;
    int r = rows[e];
    int p = atomicAdd(&fill[r], 1);
    sc[p] = make_int2(cols[e], __float_as_int(vals[e]));
}

// ---------------------------------------------------------------------------
// CSR SpMM, one wave per row, lane = latent dim (64 lanes == 64 dims).
// 8 gathers in flight per wave; edge count padded to x8 with (col=0,val=0)
// so there is no scalar tail (pad gathers hit the hot row-0 line, v=0).
// MODE 0 (layer 1): gather fp32 concat(user,item); out = 0.25*(own+acc); nxt=bf16 acc
// MODE 1 (layer 2): gather bf16 cur; out += 0.25*acc; nxt = bf16 acc
// MODE 2 (layer 3): gather bf16 cur; out += 0.25*acc
// ---------------------------------------------------------------------------
template<int MODE>
__global__ __launch_bounds__(256) void lgcn_spmm_csr(
    const int2* __restrict__ desc, const int2* __restrict__ sc,
    const float* __restrict__ user_emb, const float* __restrict__ item_emb,
    const unsigned short* __restrict__ cur, unsigned short* __restrict__ nxt,
    float* __restrict__ out)
{
    int row  = blockIdx.x * 4 + (threadIdx.x >> 6);
    int lane = threadIdx.x & 63;
    if (row >= N_NODES) return;
    int2 d = desc[row];
    int b = d.x, n = d.y;
    float acc0 = 0.f, acc1 = 0.f, acc2 = 0.f, acc3 = 0.f;

    for (int k0 = 0; k0 < n; k0 += 64) {
        int m = min(64, n - k0);
        int c = 0, vbits = 0;
        if (lane < m) {
            int2 cv = sc[b + k0 + lane];
            c = cv.x; vbits = cv.y;
        }
        int m8 = (m + 7) & ~7;
        for (int j = 0; j < m8; j += 8) {
            int   cc[8];
            float vv[8];
            #pragma unroll
            for (int t = 0; t < 8; ++t) {
                cc[t] = __shfl(c, j + t);
                vv[t] = __int_as_float(__shfl(vbits, j + t));
            }
            float x[8];
            #pragma unroll
            for (int t = 0; t < 8; ++t) {
                if constexpr (MODE == 0) {
                    x[t] = (cc[t] < NUM_USERS)
                         ? user_emb[(size_t)cc[t] * DIM + lane]
                         : item_emb[(size_t)(cc[t] - NUM_USERS) * DIM + lane];
                } else {
                    x[t] = bf2f(cur[(size_t)cc[t] * DIM + lane]);
                }
            }
            acc0 += vv[0] * x[0];
            acc1 += vv[1] * x[1];
            acc2 += vv[2] * x[2];
            acc3 += vv[3] * x[3];
            acc0 += vv[4] * x[4];
            acc1 += vv[5] * x[5];
            acc2 += vv[6] * x[6];
            acc3 += vv[7] * x[7];
        }
    }

    float acc = (acc0 + acc1) + (acc2 + acc3);
    size_t o = (size_t)row * DIM + lane;
    if constexpr (MODE == 0) {
        float own = (row < NUM_USERS)
                  ? user_emb[o]
                  : item_emb[(size_t)(row - NUM_USERS) * DIM + lane];
        nxt[o] = f2bf(acc);
        out[o] = 0.25f * (own + acc);
    } else if constexpr (MODE == 1) {
        nxt[o] = f2bf(acc);
        out[o] += 0.25f * acc;
    } else {
        out[o] += 0.25f * acc;
    }
}

extern "C" void kernel_launch(void* const* d_in, const int* in_sizes, int n_in,
                              void* d_out, int out_size, void* d_ws, size_t ws_size,
                              hipStream_t stream) {
    const float* user_emb = (const float*)d_in[0];
    const float* item_emb = (const float*)d_in[1];
    const float* vals     = (const float*)d_in[2];
    const int*   rows     = (const int*)d_in[3];
    const int*   cols     = (const int*)d_in[4];
    float* out = (float*)d_out;

    // ---- workspace carve-up (~114 MB) ----
    char* ws = (char*)d_ws;
    size_t off = 0;
    unsigned short* buf0 = (unsigned short*)(ws + off); off += N_ELEM * 2;  // 38.4 MB
    unsigned short* buf1 = (unsigned short*)(ws + off); off += N_ELEM * 2;  // 38.4 MB
    int2*  sc       = (int2*)(ws + off); off += (size_t)NNZ * 8;            // 32 MB
    int*   row_cnt  = (int*) (ws + off); off += (size_t)N_NODES * 4;        // 1.2 MB
    int*   cursor   = (int*) (ws + off); off += 256;                        // zeroed w/ cnt
    int2*  row_desc = (int2*)(ws + off); off += (size_t)N_NODES * 8;
    int*   row_fill = (int*) (ws + off); off += (size_t)N_NODES * 4;

    const int BLK = 256;
    dim3 grid_edge((NNZ + BLK - 1) / BLK);                 // 15625
    dim3 grid_edge4((NNZ / 4 + BLK - 1) / BLK);            // 3907
    dim3 grid_node((N_NODES + BLK - 1) / BLK);             // 1172
    dim3 grid_spmm((N_NODES + 3) / 4);                     // 75000 (4 rows/block)

    // ---- build CSR (once per call; ws re-poisoned before every launch) ----
    hipMemsetAsync(row_cnt, 0, (size_t)N_NODES * 4 + 256, stream);   // cnt + cursor
    lgcn_hist<<<grid_edge4, BLK, 0, stream>>>((const int4*)rows, row_cnt);
    lgcn_alloc<<<grid_node, BLK, 0, stream>>>(row_cnt, row_desc, row_fill, cursor);
    lgcn_scatter<<<grid_edge, BLK, 0, stream>>>(rows, cols, vals, row_fill, sc);

    // ---- 3 fused propagation layers ----
    lgcn_spmm_csr<0><<<grid_spmm, BLK, 0, stream>>>(
        row_desc, sc, user_emb, item_emb, nullptr, buf0, out);
    lgcn_spmm_csr<1><<<grid_spmm, BLK, 0, stream>>>(
        row_desc, sc, nullptr, nullptr, buf0, buf1, out);
    lgcn_spmm_csr<2><<<grid_spmm, BLK, 0, stream>>>(
        row_desc, sc, nullptr, nullptr, buf1, nullptr, out);
}